// Round 4
// baseline (243.691 us; speedup 1.0000x reference)
//
#include <hip/hip_runtime.h>
#include <stdint.h>

typedef unsigned short u16;
typedef __bf16  bf16x8 __attribute__((ext_vector_type(8)));
typedef u16     u16x8  __attribute__((ext_vector_type(8)));
typedef u16     u16x4  __attribute__((ext_vector_type(4)));
typedef float   f32x4  __attribute__((ext_vector_type(4)));

#define MFMA16x16x32(a, b, c) __builtin_amdgcn_mfma_f32_16x16x32_bf16((a), (b), (c), 0, 0, 0)

__device__ __forceinline__ u16 f2bf(float f) {
  uint32_t u = __float_as_uint(f);
  u += 0x7FFFu + ((u >> 16) & 1u);   // RNE
  return (u16)(u >> 16);
}

// pack hi16(a), hi16(b) -> one dword via v_perm (truncation toward zero; p>=0)
__device__ __forceinline__ uint32_t pktrunc(float a, float b) {
  return __builtin_amdgcn_perm(__float_as_uint(b), __float_as_uint(a), 0x07060302u);
}

__device__ __forceinline__ bf16x8 ldfrag(const u16* p) {
  return __builtin_bit_cast(bf16x8, *(const u16x8*)p);
}

// async global->LDS, 16B per lane. LDS dest must be wave-uniform base + lane*16.
__device__ __forceinline__ void gl2lds16(const u16* g, u16* l) {
  __builtin_amdgcn_global_load_lds(
      (__attribute__((address_space(1))) void*)g,
      (__attribute__((address_space(3))) void*)l, 16, 0, 0);
}

// ---------------- fp32 -> bf16 conversion of x, Wqkv, Wout ----------------
__global__ __launch_bounds__(256) void convert3(
    const float* __restrict__ x, const float* __restrict__ wq,
    const float* __restrict__ wo, u16* __restrict__ xb,
    u16* __restrict__ wqb, u16* __restrict__ wob) {
  const int NX = (4096 * 1024) / 8;
  const int NQ = (3072 * 1024) / 8;
  int i = blockIdx.x * 256 + threadIdx.x;   // exactly covers NX+NQ+NO
  const float* s;
  u16* d;
  if (i < NX)           { s = x;  d = xb;  }
  else if (i < NX + NQ) { s = wq; d = wqb; i -= NX; }
  else                  { s = wo; d = wob; i -= NX + NQ; }
  f32x4 a = ((const f32x4*)s)[2 * (size_t)i];
  f32x4 b = ((const f32x4*)s)[2 * (size_t)i + 1];
  u16x8 r;
  #pragma unroll
  for (int e = 0; e < 4; ++e) { r[e] = f2bf(a[e]); r[4 + e] = f2bf(b[e]); }
  ((u16x8*)d)[i] = r;
}

// ---------------- QKV projection: C[4096,3072] = X * Wqkv^T + b ----------------
// Epilogue: Q scaled by 0.125 -> (b,h,s,d); K -> (b,h,s,d); V -> TRANSPOSED (b,h,d,s)
__global__ __launch_bounds__(256) void qkv_gemm(
    const u16* __restrict__ A, const u16* __restrict__ Bw,
    const float* __restrict__ bias, u16* __restrict__ Qo,
    u16* __restrict__ Ko, u16* __restrict__ Vto) {
  __shared__ __align__(16) u16 As[128 * 32];
  __shared__ __align__(16) u16 Bs[128 * 32];

  const int t = threadIdx.x;
  const int lane = t & 63, w = t >> 6;
  const int quad = lane >> 4, col = lane & 15;
  const int wm = w & 1, wn = w >> 1;
  const int m0 = blockIdx.y * 128, n0 = blockIdx.x * 128;

  f32x4 acc[4][4] = {};

  const int ar = t >> 2, ac = (t & 3) * 8;
  const u16* Ag0 = A + (size_t)(m0 + ar) * 1024 + ac;
  const u16* Ag1 = Ag0 + 64 * 1024;
  const u16* Bg0 = Bw + (size_t)(n0 + ar) * 1024 + ac;
  const u16* Bg1 = Bg0 + 64 * 1024;
  u16* Al0 = As + t * 8;
  u16* Al1 = As + 2048 + t * 8;
  u16* Bl0 = Bs + t * 8;
  u16* Bl1 = Bs + 2048 + t * 8;

  for (int kt = 0; kt < 32; ++kt) {
    const int ko = kt * 32;
    __syncthreads();
    gl2lds16(Ag0 + ko, Al0);
    gl2lds16(Ag1 + ko, Al1);
    gl2lds16(Bg0 + ko, Bl0);
    gl2lds16(Bg1 + ko, Bl1);
    __syncthreads();

    bf16x8 bfr[4];
    #pragma unroll
    for (int j = 0; j < 4; ++j)
      bfr[j] = ldfrag(Bs + (wn * 64 + j * 16 + col) * 32 + quad * 8);
    #pragma unroll
    for (int i = 0; i < 4; ++i) {
      bf16x8 afr = ldfrag(As + (wm * 64 + i * 16 + col) * 32 + quad * 8);
      #pragma unroll
      for (int j = 0; j < 4; ++j)
        acc[i][j] = MFMA16x16x32(afr, bfr[j], acc[i][j]);
    }
  }

  #pragma unroll
  for (int i = 0; i < 4; ++i) {
    const int m = m0 + wm * 64 + i * 16 + quad * 4;  // rows m..m+3 (4-aligned)
    const int bb = m >> 11;
    const int s = m & 2047;
    #pragma unroll
    for (int j = 0; j < 4; ++j) {
      const int n = n0 + wn * 64 + j * 16 + col;
      const float bv = bias[n];
      const int which = n >> 10;          // 0=q 1=k 2=v (wave-uniform)
      const int h = (n >> 6) & 15;
      const int d = n & 63;
      if (which == 2) {
        u16x4 vv;
        #pragma unroll
        for (int r = 0; r < 4; ++r) vv[r] = f2bf(acc[i][j][r] + bv);
        *(u16x4*)(Vto + ((size_t)(bb * 16 + h) * 64 + d) * 2048 + s) = vv;
      } else {
        u16* dst = (which == 0) ? Qo : Ko;
        const float scale = (which == 0) ? 0.125f : 1.0f;  // fold 1/sqrt(64) into Q
        const size_t base = ((size_t)(bb * 16 + h) * 2048 + s) * 64 + d;
        #pragma unroll
        for (int r = 0; r < 4; ++r)
          dst[base + (size_t)r * 64] = f2bf((acc[i][j][r] + bv) * scale);
      }
    }
  }
}

// ---------------- fused attention (S^T, fat waves) ----------------
// 256 threads = 4 waves; each wave owns 32 q (two 16-q col-tiles sharing all
// K/V LDS reads). Split-pass PV (keys 0..63, then 64..127) reuses a 32x68
// per-wave P^T buffer -> LDS 49 KB. P packed by truncation (v_perm) and the
// denominator sums the SAME truncated values, so the bias cancels in O = PV/l.
__global__ __launch_bounds__(256, 2) void attn(
    const u16* __restrict__ Q, const u16* __restrict__ K,
    const u16* __restrict__ Vt, const int* __restrict__ mask,
    u16* __restrict__ AO) {
  __shared__ __align__(16) u16 Ks[128 * 64];     // [key][d], XOR chunk swizzle
  __shared__ __align__(16) u16 Vs[64 * 128];     // [d][key], XOR chunk swizzle
  __shared__ __align__(16) u16 Ps[4][32 * 68];   // per-wave P^T (64 keys), stride 68

  const int t = threadIdx.x;
  const int lane = t & 63, w = t >> 6;
  const int quad = lane >> 4, col = lane & 15;
  const int qb = blockIdx.x, bh = blockIdx.y;
  const int b = bh >> 4, h = bh & 15;

  const u16* Qh = Q + (size_t)bh * (2048 * 64);
  const u16* Kh = K + (size_t)bh * (2048 * 64);
  const u16* Vh = Vt + (size_t)bh * (64 * 2048);
  const int* mb = mask + b * 2048;

  const int qw = qb * 128 + w * 32;              // wave's first q
  bf16x8 aQ[2][2];
  #pragma unroll
  for (int ct = 0; ct < 2; ++ct) {
    #pragma unroll
    for (int kh = 0; kh < 2; ++kh)
      aQ[ct][kh] = ldfrag(Qh + (size_t)(qw + ct * 16 + col) * 64 + kh * 32 + quad * 8);
  }

  f32x4 o[2][4] = {};
  float l[2] = {0.f, 0.f};
  u16* Pw = &Ps[w][0];

  for (int kb = 0; kb < 16; ++kb) {
    const int key0 = kb * 128;
    __syncthreads();
    #pragma unroll
    for (int p = 0; p < 4; ++p) {
      int c = t + 256 * p;                       // 0..1023
      int kr = c >> 3, kc = c & 7;
      gl2lds16(Kh + (size_t)(key0 + kr) * 64 + (kc ^ (kr & 7)) * 8, Ks + c * 8);
      int vr = c >> 4, vc = c & 15;
      gl2lds16(Vh + (size_t)vr * 2048 + key0 + (vc ^ (vr & 15)) * 8, Vs + c * 8);
    }
    __syncthreads();

    // S^T = K Q^T for both col-tiles; each ak read feeds 2 MFMAs.
    f32x4 sc[2][8] = {};
    #pragma unroll
    for (int j = 0; j < 8; ++j) {
      #pragma unroll
      for (int kh = 0; kh < 2; ++kh) {
        bf16x8 ak = ldfrag(Ks + (j * 16 + col) * 64 + (((kh * 4 + quad) ^ (col & 7)) * 8));
        sc[0][j] = MFMA16x16x32(ak, aQ[0][kh], sc[0][j]);
        sc[1][j] = MFMA16x16x32(ak, aQ[1][kh], sc[1][j]);
      }
    }

    // two half-passes: softmax keys hp*64..hp*64+63 -> Ps, then PV on them
    #pragma unroll
    for (int hp = 0; hp < 2; ++hp) {
      #pragma unroll
      for (int jj = 0; jj < 4; ++jj) {
        const int j = hp * 4 + jj;
        int4 m4 = *(const int4*)(mb + key0 + j * 16 + quad * 4);
        uint32_t M01 = (m4.x ? 0x0000FFFFu : 0u) | (m4.y ? 0xFFFF0000u : 0u);
        uint32_t M23 = (m4.z ? 0x0000FFFFu : 0u) | (m4.w ? 0xFFFF0000u : 0u);
        #pragma unroll
        for (int ct = 0; ct < 2; ++ct) {
          uint32_t pkA = pktrunc(__expf(sc[ct][j][0]), __expf(sc[ct][j][1])) & M01;
          uint32_t pkB = pktrunc(__expf(sc[ct][j][2]), __expf(sc[ct][j][3])) & M23;
          // denominator from the SAME truncated+masked bf16 values
          l[ct] += (__uint_as_float(pkA << 16) + __uint_as_float(pkA & 0xFFFF0000u)) +
                   (__uint_as_float(pkB << 16) + __uint_as_float(pkB & 0xFFFF0000u));
          uint2 pk; pk.x = pkA; pk.y = pkB;
          *(uint2*)(Pw + (ct * 16 + col) * 68 + jj * 16 + quad * 4) = pk;
        }
      }

      // O^T += V^T P^T over this half's two 32-key windows
      #pragma unroll
      for (int jp = 0; jp < 2; ++jp) {
        const int gw = hp * 2 + jp;              // global 32-key window 0..3
        bf16x8 bP0 = ldfrag(Pw + col * 68 + jp * 32 + quad * 8);
        bf16x8 bP1 = ldfrag(Pw + (16 + col) * 68 + jp * 32 + quad * 8);
        #pragma unroll
        for (int dt = 0; dt < 4; ++dt) {
          bf16x8 av = ldfrag(Vs + (dt * 16 + col) * 128 + (((gw * 4 + quad) ^ col) * 8));
          o[0][dt] = MFMA16x16x32(av, bP0, o[0][dt]);
          o[1][dt] = MFMA16x16x32(av, bP1, o[1][dt]);
        }
      }
    }
  }

  // denominator: sum across the 4 quads (keys were quad-partitioned)
  #pragma unroll
  for (int ct = 0; ct < 2; ++ct) {
    float s = l[ct];
    s += __shfl_xor(s, 16);
    s += __shfl_xor(s, 32);
    l[ct] = 1.0f / s;
  }

  #pragma unroll
  for (int ct = 0; ct < 2; ++ct) {
    const int q = qw + ct * 16 + col;
    #pragma unroll
    for (int dt = 0; dt < 4; ++dt) {
      u16x4 v;
      #pragma unroll
      for (int r = 0; r < 4; ++r) v[r] = f2bf(o[ct][dt][r] * l[ct]);
      *(u16x4*)(AO + (size_t)(b * 2048 + q) * 1024 + h * 64 + dt * 16 + quad * 4) = v;
    }
  }
}

// ---------------- output projection: out = AO * Wout^T + bout (fp32 out) ----------------
__global__ __launch_bounds__(256) void proj_gemm(
    const u16* __restrict__ A, const u16* __restrict__ Bw,
    const float* __restrict__ bias, float* __restrict__ out) {
  __shared__ __align__(16) u16 As[128 * 32];
  __shared__ __align__(16) u16 Bs[128 * 32];

  const int t = threadIdx.x;
  const int lane = t & 63, w = t >> 6;
  const int quad = lane >> 4, col = lane & 15;
  const int wm = w & 1, wn = w >> 1;
  const int m0 = blockIdx.y * 128, n0 = blockIdx.x * 128;

  f32x4 acc[4][4] = {};

  const int ar = t >> 2, ac = (t & 3) * 8;
  const u16* Ag0 = A + (size_t)(m0 + ar) * 1024 + ac;
  const u16* Ag1 = Ag0 + 64 * 1024;
  const u16* Bg0 = Bw + (size_t)(n0 + ar) * 1024 + ac;
  const u16* Bg1 = Bg0 + 64 * 1024;
  u16* Al0 = As + t * 8;
  u16* Al1 = As + 2048 + t * 8;
  u16* Bl0 = Bs + t * 8;
  u16* Bl1 = Bs + 2048 + t * 8;

  for (int kt = 0; kt < 32; ++kt) {
    const int ko = kt * 32;
    __syncthreads();
    gl2lds16(Ag0 + ko, Al0);
    gl2lds16(Ag1 + ko, Al1);
    gl2lds16(Bg0 + ko, Bl0);
    gl2lds16(Bg1 + ko, Bl1);
    __syncthreads();

    bf16x8 bfr[4];
    #pragma unroll
    for (int j = 0; j < 4; ++j)
      bfr[j] = ldfrag(Bs + (wn * 64 + j * 16 + col) * 32 + quad * 8);
    #pragma unroll
    for (int i = 0; i < 4; ++i) {
      bf16x8 afr = ldfrag(As + (wm * 64 + i * 16 + col) * 32 + quad * 8);
      #pragma unroll
      for (int j = 0; j < 4; ++j)
        acc[i][j] = MFMA16x16x32(afr, bfr[j], acc[i][j]);
    }
  }

  #pragma unroll
  for (int i = 0; i < 4; ++i) {
    const int m = m0 + wm * 64 + i * 16 + quad * 4;
    #pragma unroll
    for (int j = 0; j < 4; ++j) {
      const int n = n0 + wn * 64 + j * 16 + col;
      const float bv = bias[n];
      #pragma unroll
      for (int r = 0; r < 4; ++r)
        out[(size_t)(m + r) * 1024 + n] = acc[i][j][r] + bv;
    }
  }
}

extern "C" void kernel_launch(void* const* d_in, const int* in_sizes, int n_in,
                              void* d_out, int out_size, void* d_ws, size_t ws_size,
                              hipStream_t stream) {
  (void)in_sizes; (void)n_in; (void)out_size; (void)ws_size;
  const float* x    = (const float*)d_in[0];
  const int*   mask = (const int*)d_in[1];
  const float* Wqkv = (const float*)d_in[2];
  const float* bqkv = (const float*)d_in[3];
  const float* Wout = (const float*)d_in[4];
  const float* bout = (const float*)d_in[5];
  float* out = (float*)d_out;
  char* ws = (char*)d_ws;

  u16* Xb  = (u16*)(ws);                         // 8 MiB (reused as AO later)
  u16* Wqb = (u16*)(ws + ((size_t)8  << 20));    // 6 MiB
  u16* Wob = (u16*)(ws + ((size_t)14 << 20));    // 2 MiB
  u16* Qb  = (u16*)(ws + ((size_t)16 << 20));    // 8 MiB
  u16* Kb  = (u16*)(ws + ((size_t)24 << 20));    // 8 MiB
  u16* Vtb = (u16*)(ws + ((size_t)32 << 20));    // 8 MiB (V stored pre-transposed)
  u16* AO  = Xb;  // X is dead after qkv_gemm

  convert3<<<dim3(4096), dim3(256), 0, stream>>>(x, Wqkv, Wout, Xb, Wqb, Wob);
  qkv_gemm<<<dim3(24, 32), dim3(256), 0, stream>>>(Xb, Wqb, bqkv, Qb, Kb, Vtb);
  attn<<<dim3(16, 32), dim3(256), 0, stream>>>(Qb, Kb, Vtb, mask, AO);
  proj_gemm<<<dim3(8, 32), dim3(256), 0, stream>>>(AO, Wob, bout, out);
}

// Round 5
// 208.509 us; speedup vs baseline: 1.1687x; 1.1687x over previous
//
#include <hip/hip_runtime.h>
#include <stdint.h>

typedef unsigned short u16;
typedef __bf16  bf16x8 __attribute__((ext_vector_type(8)));
typedef u16     u16x8  __attribute__((ext_vector_type(8)));
typedef u16     u16x4  __attribute__((ext_vector_type(4)));
typedef float   f32x4  __attribute__((ext_vector_type(4)));

#define MFMA16x16x32(a, b, c) __builtin_amdgcn_mfma_f32_16x16x32_bf16((a), (b), (c), 0, 0, 0)

__device__ __forceinline__ u16 f2bf(float f) {
  uint32_t u = __float_as_uint(f);
  u += 0x7FFFu + ((u >> 16) & 1u);   // RNE
  return (u16)(u >> 16);
}

// pack hi16(a), hi16(b) -> one dword via v_perm (truncation toward zero; p>=0)
__device__ __forceinline__ uint32_t pktrunc(float a, float b) {
  return __builtin_amdgcn_perm(__float_as_uint(b), __float_as_uint(a), 0x07060302u);
}

__device__ __forceinline__ bf16x8 ldfrag(const u16* p) {
  return __builtin_bit_cast(bf16x8, *(const u16x8*)p);
}

// async global->LDS, 16B per lane. LDS dest must be wave-uniform base + lane*16.
__device__ __forceinline__ void gl2lds16(const u16* g, u16* l) {
  __builtin_amdgcn_global_load_lds(
      (__attribute__((address_space(1))) void*)g,
      (__attribute__((address_space(3))) void*)l, 16, 0, 0);
}

// ---------------- fp32 -> bf16 conversion of x, Wqkv, Wout ----------------
__global__ __launch_bounds__(256) void convert3(
    const float* __restrict__ x, const float* __restrict__ wq,
    const float* __restrict__ wo, u16* __restrict__ xb,
    u16* __restrict__ wqb, u16* __restrict__ wob) {
  const int NX = (4096 * 1024) / 8;
  const int NQ = (3072 * 1024) / 8;
  int i = blockIdx.x * 256 + threadIdx.x;   // exactly covers NX+NQ+NO
  const float* s;
  u16* d;
  if (i < NX)           { s = x;  d = xb;  }
  else if (i < NX + NQ) { s = wq; d = wqb; i -= NX; }
  else                  { s = wo; d = wob; i -= NX + NQ; }
  f32x4 a = ((const f32x4*)s)[2 * (size_t)i];
  f32x4 b = ((const f32x4*)s)[2 * (size_t)i + 1];
  u16x8 r;
  #pragma unroll
  for (int e = 0; e < 4; ++e) { r[e] = f2bf(a[e]); r[4 + e] = f2bf(b[e]); }
  ((u16x8*)d)[i] = r;
}

// ---------------- QKV projection: C[4096,3072] = X * Wqkv^T + b ----------------
// Epilogue scatters bf16 into Q/K/V laid out (b,h,s,d); Q scaled by 0.125.
__global__ __launch_bounds__(256) void qkv_gemm(
    const u16* __restrict__ A, const u16* __restrict__ Bw,
    const float* __restrict__ bias, u16* __restrict__ Qo,
    u16* __restrict__ Ko, u16* __restrict__ Vo) {
  __shared__ __align__(16) u16 As[128 * 32];
  __shared__ __align__(16) u16 Bs[128 * 32];

  const int t = threadIdx.x;
  const int lane = t & 63, w = t >> 6;
  const int quad = lane >> 4, col = lane & 15;
  const int wm = w & 1, wn = w >> 1;
  const int m0 = blockIdx.y * 128, n0 = blockIdx.x * 128;

  f32x4 acc[4][4] = {};

  const int ar = t >> 2, ac = (t & 3) * 8;
  const u16* Ag0 = A + (size_t)(m0 + ar) * 1024 + ac;
  const u16* Ag1 = Ag0 + 64 * 1024;
  const u16* Bg0 = Bw + (size_t)(n0 + ar) * 1024 + ac;
  const u16* Bg1 = Bg0 + 64 * 1024;
  u16* Al0 = As + t * 8;
  u16* Al1 = As + 2048 + t * 8;
  u16* Bl0 = Bs + t * 8;
  u16* Bl1 = Bs + 2048 + t * 8;

  for (int kt = 0; kt < 32; ++kt) {
    const int ko = kt * 32;
    __syncthreads();
    gl2lds16(Ag0 + ko, Al0);
    gl2lds16(Ag1 + ko, Al1);
    gl2lds16(Bg0 + ko, Bl0);
    gl2lds16(Bg1 + ko, Bl1);
    __syncthreads();

    bf16x8 bfr[4];
    #pragma unroll
    for (int j = 0; j < 4; ++j)
      bfr[j] = ldfrag(Bs + (wn * 64 + j * 16 + col) * 32 + quad * 8);
    #pragma unroll
    for (int i = 0; i < 4; ++i) {
      bf16x8 afr = ldfrag(As + (wm * 64 + i * 16 + col) * 32 + quad * 8);
      #pragma unroll
      for (int j = 0; j < 4; ++j)
        acc[i][j] = MFMA16x16x32(afr, bfr[j], acc[i][j]);
    }
  }

  #pragma unroll
  for (int i = 0; i < 4; ++i) {
    const int m = m0 + wm * 64 + i * 16 + quad * 4;  // rows m..m+3 (4-aligned)
    const int bb = m >> 11;
    const int s = m & 2047;
    #pragma unroll
    for (int j = 0; j < 4; ++j) {
      const int n = n0 + wn * 64 + j * 16 + col;
      const float bv = bias[n];
      const int which = n >> 10;          // 0=q 1=k 2=v (wave-uniform)
      const int h = (n >> 6) & 15;
      const int d = n & 63;
      u16* dst = (which == 0) ? Qo : ((which == 1) ? Ko : Vo);
      const float scale = (which == 0) ? 0.125f : 1.0f;  // fold 1/sqrt(64) into Q
      const size_t base = ((size_t)(bb * 16 + h) * 2048 + s) * 64 + d;
      #pragma unroll
      for (int r = 0; r < 4; ++r)
        dst[base + (size_t)r * 64] = f2bf((acc[i][j][r] + bv) * scale);
    }
  }
}

// ---------------- V (b,h,s,d) -> Vt (b,h,d,s) 64x64-tile transpose ----------------
__global__ __launch_bounds__(256) void transpose64(
    const u16* __restrict__ V, u16* __restrict__ Vt) {
  __shared__ u16 tile[64][72];
  const int t = threadIdx.x;
  const int s0 = blockIdx.x * 64;
  const int bh = blockIdx.y;
  const u16* Vb = V + (size_t)bh * (2048 * 64);
  u16* Vtb = Vt + (size_t)bh * (64 * 2048);
  #pragma unroll
  for (int p = 0; p < 2; ++p) {
    int c = t + 256 * p;
    int r = c >> 3, c8 = (c & 7) * 8;
    u16x8 v = *(const u16x8*)(Vb + (size_t)(s0 + r) * 64 + c8);
    #pragma unroll
    for (int e = 0; e < 8; ++e) tile[r][c8 + e] = v[e];
  }
  __syncthreads();
  #pragma unroll
  for (int p = 0; p < 2; ++p) {
    int c = t + 256 * p;
    int dr = c >> 3, c8 = (c & 7) * 8;
    u16x8 v;
    #pragma unroll
    for (int e = 0; e < 8; ++e) v[e] = tile[c8 + e][dr];
    *(u16x8*)(Vtb + (size_t)dr * 2048 + s0 + c8) = v;
  }
}

// ---------------- fused attention (S^T, fat waves, split-K pairs) ----------------
// 512 threads = 8 fat waves, each owning 32 q (two 16-q col-tiles sharing all
// K/V LDS reads). Wave pair u = w>>1 covers the same 32 q; group g = w&1 takes
// keys g*64..g*64+63 of every 128-key tile. No online-max -> partial (O, l) are
// purely additive; combined once at the end through an XOR-swizzled LDS buffer.
// P packed by truncation (v_perm); denominator sums the SAME truncated values,
// so the truncation bias cancels in O = PV / l.
__global__ __launch_bounds__(512, 4) void attn(
    const u16* __restrict__ Q, const u16* __restrict__ K,
    const u16* __restrict__ Vt, const int* __restrict__ mask,
    u16* __restrict__ AO) {
  __shared__ __align__(16) u16 Ks[128 * 64];     // [key][d], XOR chunk swizzle
  __shared__ __align__(16) u16 Vs[64 * 128];     // [d][key], XOR chunk swizzle
  __shared__ __align__(16) u16 Ps[8][32 * 72];   // per-wave P^T (64 keys), stride 72

  const int t = threadIdx.x;
  const int lane = t & 63, w = t >> 6;
  const int quad = lane >> 4, col = lane & 15;
  const int g = w & 1, u = w >> 1;
  const int qb = blockIdx.x, bh = blockIdx.y;
  const int b = bh >> 4, h = bh & 15;

  const u16* Qh = Q + (size_t)bh * (2048 * 64);
  const u16* Kh = K + (size_t)bh * (2048 * 64);
  const u16* Vh = Vt + (size_t)bh * (64 * 2048);
  const int* mb = mask + b * 2048;

  const int qw = qb * 128 + u * 32;              // wave-pair's first q
  const int keyg = g * 64;                       // this wave's key half
  bf16x8 aQ[2][2];
  #pragma unroll
  for (int ct = 0; ct < 2; ++ct) {
    #pragma unroll
    for (int kh = 0; kh < 2; ++kh)
      aQ[ct][kh] = ldfrag(Qh + (size_t)(qw + ct * 16 + col) * 64 + kh * 32 + quad * 8);
  }

  f32x4 o[2][4] = {};
  float l[2] = {0.f, 0.f};
  u16* Pw = &Ps[w][0];

  for (int kb = 0; kb < 16; ++kb) {
    const int key0 = kb * 128;
    __syncthreads();
    #pragma unroll
    for (int p = 0; p < 2; ++p) {
      int c = t + 512 * p;                       // 0..1023
      int kr = c >> 3, kc = c & 7;
      gl2lds16(Kh + (size_t)(key0 + kr) * 64 + (kc ^ (kr & 7)) * 8, Ks + c * 8);
      int vr = c >> 4, vc = c & 15;
      gl2lds16(Vh + (size_t)vr * 2048 + key0 + (vc ^ (vr & 15)) * 8, Vs + c * 8);
    }
    __syncthreads();

    // S^T = K Q^T for this wave's 64-key half; each ak read feeds 2 MFMAs.
    f32x4 sc[2][4] = {};
    #pragma unroll
    for (int j = 0; j < 4; ++j) {
      #pragma unroll
      for (int kh = 0; kh < 2; ++kh) {
        bf16x8 ak = ldfrag(Ks + (keyg + j * 16 + col) * 64 + (((kh * 4 + quad) ^ (col & 7)) * 8));
        sc[0][j] = MFMA16x16x32(ak, aQ[0][kh], sc[0][j]);
        sc[1][j] = MFMA16x16x32(ak, aQ[1][kh], sc[1][j]);
      }
    }

    // softmax numerators for the 64-key half -> Ps
    #pragma unroll
    for (int jj = 0; jj < 4; ++jj) {
      int4 m4 = *(const int4*)(mb + key0 + keyg + jj * 16 + quad * 4);
      uint32_t M01 = (m4.x ? 0x0000FFFFu : 0u) | (m4.y ? 0xFFFF0000u : 0u);
      uint32_t M23 = (m4.z ? 0x0000FFFFu : 0u) | (m4.w ? 0xFFFF0000u : 0u);
      #pragma unroll
      for (int ct = 0; ct < 2; ++ct) {
        uint32_t pkA = pktrunc(__expf(sc[ct][jj][0]), __expf(sc[ct][jj][1])) & M01;
        uint32_t pkB = pktrunc(__expf(sc[ct][jj][2]), __expf(sc[ct][jj][3])) & M23;
        // denominator from the SAME truncated+masked bf16 values
        l[ct] += (__uint_as_float(pkA << 16) + __uint_as_float(pkA & 0xFFFF0000u)) +
                 (__uint_as_float(pkB << 16) + __uint_as_float(pkB & 0xFFFF0000u));
        uint2 pk; pk.x = pkA; pk.y = pkB;
        *(uint2*)(Pw + (ct * 16 + col) * 72 + jj * 16 + quad * 4) = pk;
      }
    }

    // O^T += V^T P^T over this half's two 32-key windows
    #pragma unroll
    for (int jp = 0; jp < 2; ++jp) {
      bf16x8 bP0 = ldfrag(Pw + col * 72 + jp * 32 + quad * 8);
      bf16x8 bP1 = ldfrag(Pw + (16 + col) * 72 + jp * 32 + quad * 8);
      #pragma unroll
      for (int dt = 0; dt < 4; ++dt) {
        bf16x8 av = ldfrag(Vs + (dt * 16 + col) * 128 + (((g * 8 + jp * 4 + quad) ^ col) * 8));
        o[0][dt] = MFMA16x16x32(av, bP0, o[0][dt]);
        o[1][dt] = MFMA16x16x32(av, bP1, o[1][dt]);
      }
    }
  }

  // combine wave-pair partials (additive: no online-max rescaling exists)
  __syncthreads();
  float* Rb = (float*)(&Ps[0][0]);
  float* Ro = Rb + u * 2048 + lane * 32;         // 32 f32/lane, 16B-aligned
  float* Rl = Rb + 8192 + u * 128 + lane * 2;
  if (g == 1) {
    #pragma unroll
    for (int ct = 0; ct < 2; ++ct)
      #pragma unroll
      for (int dt = 0; dt < 4; ++dt)
        *(f32x4*)(Ro + ((ct * 4 + dt) ^ (lane & 7)) * 4) = o[ct][dt];
    Rl[0] = l[0]; Rl[1] = l[1];
  }
  __syncthreads();
  if (g == 0) {
    #pragma unroll
    for (int ct = 0; ct < 2; ++ct) {
      #pragma unroll
      for (int dt = 0; dt < 4; ++dt)
        o[ct][dt] += *(const f32x4*)(Ro + ((ct * 4 + dt) ^ (lane & 7)) * 4);
      float s = l[ct] + Rl[ct];
      s += __shfl_xor(s, 16);
      s += __shfl_xor(s, 32);
      l[ct] = 1.0f / s;
    }
    #pragma unroll
    for (int ct = 0; ct < 2; ++ct) {
      const int q = qw + ct * 16 + col;
      #pragma unroll
      for (int dt = 0; dt < 4; ++dt) {
        u16x4 v;
        #pragma unroll
        for (int r = 0; r < 4; ++r) v[r] = f2bf(o[ct][dt][r] * l[ct]);
        *(u16x4*)(AO + (size_t)(b * 2048 + q) * 1024 + h * 64 + dt * 16 + quad * 4) = v;
      }
    }
  }
}

// ---------------- output projection: out = AO * Wout^T + bout (fp32 out) ----------------
__global__ __launch_bounds__(256) void proj_gemm(
    const u16* __restrict__ A, const u16* __restrict__ Bw,
    const float* __restrict__ bias, float* __restrict__ out) {
  __shared__ __align__(16) u16 As[128 * 32];
  __shared__ __align__(16) u16 Bs[128 * 32];

  const int t = threadIdx.x;
  const int lane = t & 63, w = t >> 6;
  const int quad = lane >> 4, col = lane & 15;
  const int wm = w & 1, wn = w >> 1;
  const int m0 = blockIdx.y * 128, n0 = blockIdx.x * 128;

  f32x4 acc[4][4] = {};

  const int ar = t >> 2, ac = (t & 3) * 8;
  const u16* Ag0 = A + (size_t)(m0 + ar) * 1024 + ac;
  const u16* Ag1 = Ag0 + 64 * 1024;
  const u16* Bg0 = Bw + (size_t)(n0 + ar) * 1024 + ac;
  const u16* Bg1 = Bg0 + 64 * 1024;
  u16* Al0 = As + t * 8;
  u16* Al1 = As + 2048 + t * 8;
  u16* Bl0 = Bs + t * 8;
  u16* Bl1 = Bs + 2048 + t * 8;

  for (int kt = 0; kt < 32; ++kt) {
    const int ko = kt * 32;
    __syncthreads();
    gl2lds16(Ag0 + ko, Al0);
    gl2lds16(Ag1 + ko, Al1);
    gl2lds16(Bg0 + ko, Bl0);
    gl2lds16(Bg1 + ko, Bl1);
    __syncthreads();

    bf16x8 bfr[4];
    #pragma unroll
    for (int j = 0; j < 4; ++j)
      bfr[j] = ldfrag(Bs + (wn * 64 + j * 16 + col) * 32 + quad * 8);
    #pragma unroll
    for (int i = 0; i < 4; ++i) {
      bf16x8 afr = ldfrag(As + (wm * 64 + i * 16 + col) * 32 + quad * 8);
      #pragma unroll
      for (int j = 0; j < 4; ++j)
        acc[i][j] = MFMA16x16x32(afr, bfr[j], acc[i][j]);
    }
  }

  #pragma unroll
  for (int i = 0; i < 4; ++i) {
    const int m = m0 + wm * 64 + i * 16 + quad * 4;
    #pragma unroll
    for (int j = 0; j < 4; ++j) {
      const int n = n0 + wn * 64 + j * 16 + col;
      const float bv = bias[n];
      #pragma unroll
      for (int r = 0; r < 4; ++r)
        out[(size_t)(m + r) * 1024 + n] = acc[i][j][r] + bv;
    }
  }
}

extern "C" void kernel_launch(void* const* d_in, const int* in_sizes, int n_in,
                              void* d_out, int out_size, void* d_ws, size_t ws_size,
                              hipStream_t stream) {
  (void)in_sizes; (void)n_in; (void)out_size; (void)ws_size;
  const float* x    = (const float*)d_in[0];
  const int*   mask = (const int*)d_in[1];
  const float* Wqkv = (const float*)d_in[2];
  const float* bqkv = (const float*)d_in[3];
  const float* Wout = (const float*)d_in[4];
  const float* bout = (const float*)d_in[5];
  float* out = (float*)d_out;
  char* ws = (char*)d_ws;

  u16* Xb  = (u16*)(ws);                         // 8 MiB (reused as AO later)
  u16* Wqb = (u16*)(ws + ((size_t)8  << 20));    // 6 MiB
  u16* Wob = (u16*)(ws + ((size_t)14 << 20));    // 2 MiB
  u16* Qb  = (u16*)(ws + ((size_t)16 << 20));    // 8 MiB
  u16* Kb  = (u16*)(ws + ((size_t)24 << 20));    // 8 MiB
  u16* Vb  = (u16*)(ws + ((size_t)32 << 20));    // 8 MiB
  u16* Vtb = (u16*)(ws + ((size_t)40 << 20));    // 8 MiB  (total 48 MiB)
  u16* AO  = Xb;  // X is dead after qkv_gemm

  convert3<<<dim3(4096), dim3(256), 0, stream>>>(x, Wqkv, Wout, Xb, Wqb, Wob);
  qkv_gemm<<<dim3(24, 32), dim3(256), 0, stream>>>(Xb, Wqb, bqkv, Qb, Kb, Vb);
  transpose64<<<dim3(32, 32), dim3(256), 0, stream>>>(Vb, Vtb);
  attn<<<dim3(16, 32), dim3(512), 0, stream>>>(Qb, Kb, Vtb, mask, AO);
  proj_gemm<<<dim3(8, 32), dim3(256), 0, stream>>>(AO, Wob, bout, out);
}

// Round 6
// 204.419 us; speedup vs baseline: 1.1921x; 1.0200x over previous
//
#include <hip/hip_runtime.h>
#include <stdint.h>

typedef unsigned short u16;
typedef __bf16    bf16x8 __attribute__((ext_vector_type(8)));
typedef u16       u16x8  __attribute__((ext_vector_type(8)));
typedef u16       u16x4  __attribute__((ext_vector_type(4)));
typedef float     f32x4  __attribute__((ext_vector_type(4)));
typedef uint32_t  u32x4  __attribute__((ext_vector_type(4)));

#define MFMA16x16x32(a, b, c) __builtin_amdgcn_mfma_f32_16x16x32_bf16((a), (b), (c), 0, 0, 0)

__device__ __forceinline__ u16 f2bf(float f) {
  uint32_t u = __float_as_uint(f);
  u += 0x7FFFu + ((u >> 16) & 1u);   // RNE
  return (u16)(u >> 16);
}

// pack hi16(a), hi16(b) -> one dword via v_perm (truncation toward zero; p>=0)
__device__ __forceinline__ uint32_t pktrunc(float a, float b) {
  return __builtin_amdgcn_perm(__float_as_uint(b), __float_as_uint(a), 0x07060302u);
}

__device__ __forceinline__ bf16x8 ldfrag(const u16* p) {
  return __builtin_bit_cast(bf16x8, *(const u16x8*)p);
}

// 16B fragment from two 8B LDS reads (8B-aligned, bank-clean at stride 68)
__device__ __forceinline__ bf16x8 ldfrag2(const u16* p) {
  uint2 a = *(const uint2*)p;
  uint2 b = *(const uint2*)(p + 4);
  u32x4 t; t[0] = a.x; t[1] = a.y; t[2] = b.x; t[3] = b.y;
  return __builtin_bit_cast(bf16x8, t);
}

// async global->LDS, 16B per lane. LDS dest must be wave-uniform base + lane*16.
__device__ __forceinline__ void gl2lds16(const u16* g, u16* l) {
  __builtin_amdgcn_global_load_lds(
      (__attribute__((address_space(1))) void*)g,
      (__attribute__((address_space(3))) void*)l, 16, 0, 0);
}

// ---------------- fp32 -> bf16 conversion of x, Wqkv, Wout ----------------
__global__ __launch_bounds__(256) void convert3(
    const float* __restrict__ x, const float* __restrict__ wq,
    const float* __restrict__ wo, u16* __restrict__ xb,
    u16* __restrict__ wqb, u16* __restrict__ wob) {
  const int NX = (4096 * 1024) / 8;
  const int NQ = (3072 * 1024) / 8;
  int i = blockIdx.x * 256 + threadIdx.x;   // exactly covers NX+NQ+NO
  const float* s;
  u16* d;
  if (i < NX)           { s = x;  d = xb;  }
  else if (i < NX + NQ) { s = wq; d = wqb; i -= NX; }
  else                  { s = wo; d = wob; i -= NX + NQ; }
  f32x4 a = ((const f32x4*)s)[2 * (size_t)i];
  f32x4 b = ((const f32x4*)s)[2 * (size_t)i + 1];
  u16x8 r;
  #pragma unroll
  for (int e = 0; e < 4; ++e) { r[e] = f2bf(a[e]); r[4 + e] = f2bf(b[e]); }
  ((u16x8*)d)[i] = r;
}

// ---------------- QKV projection: C[4096,3072] = X * Wqkv^T + b ----------------
// BK=64, XOR chunk-swizzled LDS (bank-uniform b128 frag reads), swapped-operand
// MFMA (acc holds C^T subtiles: lane's 4 regs = 4 consecutive n = d) so the
// epilogue stores u16x4. Q scaled by 0.125; Q/K/V in (b,h,s,d).
__global__ __launch_bounds__(256) void qkv_gemm(
    const u16* __restrict__ A, const u16* __restrict__ Bw,
    const float* __restrict__ bias, u16* __restrict__ Qo,
    u16* __restrict__ Ko, u16* __restrict__ Vo) {
  __shared__ __align__(16) u16 As[128 * 64];
  __shared__ __align__(16) u16 Bs[128 * 64];

  const int t = threadIdx.x;
  const int lane = t & 63, w = t >> 6;
  const int quad = lane >> 4, col = lane & 15;
  const int wm = w & 1, wn = w >> 1;
  const int m0 = blockIdx.y * 128, n0 = blockIdx.x * 128;

  f32x4 acc[4][4] = {};   // acc[i][j] = C^T tile: rows n (j), lane-cols m (i)

  for (int kt = 0; kt < 16; ++kt) {
    const int ko = kt * 64;
    __syncthreads();
    #pragma unroll
    for (int p = 0; p < 4; ++p) {
      int c = t + 256 * p;                  // 0..1023
      int r = c >> 3, cc = c & 7;
      int so = ko + ((cc ^ (r & 7)) * 8);
      gl2lds16(A  + (size_t)(m0 + r) * 1024 + so, As + c * 8);
      gl2lds16(Bw + (size_t)(n0 + r) * 1024 + so, Bs + c * 8);
    }
    __syncthreads();

    #pragma unroll
    for (int kk = 0; kk < 2; ++kk) {
      const int e8 = ((kk * 4 + quad) ^ (col & 7)) * 8;
      bf16x8 bfr[4];
      #pragma unroll
      for (int j = 0; j < 4; ++j)
        bfr[j] = ldfrag(Bs + (wn * 64 + j * 16 + col) * 64 + e8);
      #pragma unroll
      for (int i = 0; i < 4; ++i) {
        bf16x8 afr = ldfrag(As + (wm * 64 + i * 16 + col) * 64 + e8);
        #pragma unroll
        for (int j = 0; j < 4; ++j)
          acc[i][j] = MFMA16x16x32(bfr[j], afr, acc[i][j]);  // C^T
      }
    }
  }

  const int nb = n0 + wn * 64;              // wave covers one 64-wide head slice
  const int which = nb >> 10;               // 0=q 1=k 2=v (wave-uniform)
  const int h = (nb >> 6) & 15;
  u16* dst = (which == 0) ? Qo : ((which == 1) ? Ko : Vo);
  const float scale = (which == 0) ? 0.125f : 1.0f;

  #pragma unroll
  for (int j = 0; j < 4; ++j) {
    const f32x4 b4 = *(const f32x4*)(bias + nb + j * 16 + quad * 4);
    #pragma unroll
    for (int i = 0; i < 4; ++i) {
      const int m = m0 + wm * 64 + i * 16 + col;
      const int bb = m >> 11, s = m & 2047;
      u16x4 vv;
      #pragma unroll
      for (int r = 0; r < 4; ++r) vv[r] = f2bf((acc[i][j][r] + b4[r]) * scale);
      *(u16x4*)(dst + ((size_t)(bb * 16 + h) * 2048 + s) * 64 + j * 16 + quad * 4) = vv;
    }
  }
}

// ---------------- V (b,h,s,d) -> Vt (b,h,d,s) 64x64-tile transpose ----------------
__global__ __launch_bounds__(256) void transpose64(
    const u16* __restrict__ V, u16* __restrict__ Vt) {
  __shared__ u16 tile[64][72];
  const int t = threadIdx.x;
  const int s0 = blockIdx.x * 64;
  const int bh = blockIdx.y;
  const u16* Vb = V + (size_t)bh * (2048 * 64);
  u16* Vtb = Vt + (size_t)bh * (64 * 2048);
  #pragma unroll
  for (int p = 0; p < 2; ++p) {
    int c = t + 256 * p;
    int r = c >> 3, c8 = (c & 7) * 8;
    u16x8 v = *(const u16x8*)(Vb + (size_t)(s0 + r) * 64 + c8);
    #pragma unroll
    for (int e = 0; e < 8; ++e) tile[r][c8 + e] = v[e];
  }
  __syncthreads();
  #pragma unroll
  for (int p = 0; p < 2; ++p) {
    int c = t + 256 * p;
    int dr = c >> 3, c8 = (c & 7) * 8;
    u16x8 v;
    #pragma unroll
    for (int e = 0; e < 8; ++e) v[e] = tile[c8 + e][dr];
    *(u16x8*)(Vtb + (size_t)dr * 2048 + s0 + c8) = v;
  }
}

// ---------------- fused attention (S^T, fat waves, split-K pairs) ----------------
// 512 threads = 8 fat waves, each owning 32 q (two 16-q col-tiles sharing all
// K/V LDS reads). Wave pair u = w>>1 covers the same 32 q; group g = w&1 takes
// keys g*64..g*64+63. Partials (O,l) additive; combined once via LDS.
// Denominator computed by MFMA with a ones A-fragment (every lane's lacc = its
// q-column's sum) - no VALU unpack, no shuffle reduce. P packed by truncation;
// l sums the SAME truncated values so the bias cancels in O = PV/l.
__global__ __launch_bounds__(512, 4) void attn(
    const u16* __restrict__ Q, const u16* __restrict__ K,
    const u16* __restrict__ Vt, const int* __restrict__ mask,
    u16* __restrict__ AO) {
  __shared__ __align__(16) u16 Ks[128 * 64];     // [key][d], XOR chunk swizzle
  __shared__ __align__(16) u16 Vs[64 * 128];     // [d][key], XOR chunk swizzle
  __shared__ __align__(16) u16 Ps[8][32 * 68];   // per-wave P^T (64 keys), stride 68

  const int t = threadIdx.x;
  const int lane = t & 63, w = t >> 6;
  const int quad = lane >> 4, col = lane & 15;
  const int g = w & 1, u = w >> 1;
  const int qb = blockIdx.x, bh = blockIdx.y;
  const int b = bh >> 4, h = bh & 15;

  const u16* Qh = Q + (size_t)bh * (2048 * 64);
  const u16* Kh = K + (size_t)bh * (2048 * 64);
  const u16* Vh = Vt + (size_t)bh * (64 * 2048);
  const int* mb = mask + b * 2048;

  u16x8 ou;
  #pragma unroll
  for (int e = 0; e < 8; ++e) ou[e] = 0x3F80;    // bf16 1.0
  const bf16x8 ones = __builtin_bit_cast(bf16x8, ou);

  const int qw = qb * 128 + u * 32;              // wave-pair's first q
  const int keyg = g * 64;                       // this wave's key half
  bf16x8 aQ[2][2];
  #pragma unroll
  for (int ct = 0; ct < 2; ++ct) {
    #pragma unroll
    for (int kh = 0; kh < 2; ++kh)
      aQ[ct][kh] = ldfrag(Qh + (size_t)(qw + ct * 16 + col) * 64 + kh * 32 + quad * 8);
  }

  f32x4 o[2][4] = {};
  f32x4 lacc[2] = {};
  u16* Pw = &Ps[w][0];

  for (int kb = 0; kb < 16; ++kb) {
    const int key0 = kb * 128;
    __syncthreads();
    #pragma unroll
    for (int p = 0; p < 2; ++p) {
      int c = t + 512 * p;                       // 0..1023
      int kr = c >> 3, kc = c & 7;
      gl2lds16(Kh + (size_t)(key0 + kr) * 64 + (kc ^ (kr & 7)) * 8, Ks + c * 8);
      int vr = c >> 4, vc = c & 15;
      gl2lds16(Vh + (size_t)vr * 2048 + key0 + (vc ^ (vr & 15)) * 8, Vs + c * 8);
    }
    __syncthreads();

    // S^T = K Q^T for this wave's 64-key half; each ak read feeds 2 MFMAs.
    f32x4 sc[2][4] = {};
    #pragma unroll
    for (int j = 0; j < 4; ++j) {
      #pragma unroll
      for (int kh = 0; kh < 2; ++kh) {
        bf16x8 ak = ldfrag(Ks + (keyg + j * 16 + col) * 64 + (((kh * 4 + quad) ^ (col & 7)) * 8));
        sc[0][j] = MFMA16x16x32(ak, aQ[0][kh], sc[0][j]);
        sc[1][j] = MFMA16x16x32(ak, aQ[1][kh], sc[1][j]);
      }
    }

    // softmax numerators for the 64-key half -> Ps (truncation-packed, masked)
    #pragma unroll
    for (int jj = 0; jj < 4; ++jj) {
      int4 m4 = *(const int4*)(mb + key0 + keyg + jj * 16 + quad * 4);
      uint32_t M01 = (m4.x ? 0x0000FFFFu : 0u) | (m4.y ? 0xFFFF0000u : 0u);
      uint32_t M23 = (m4.z ? 0x0000FFFFu : 0u) | (m4.w ? 0xFFFF0000u : 0u);
      #pragma unroll
      for (int ct = 0; ct < 2; ++ct) {
        uint2 pk;
        pk.x = pktrunc(__expf(sc[ct][jj][0]), __expf(sc[ct][jj][1])) & M01;
        pk.y = pktrunc(__expf(sc[ct][jj][2]), __expf(sc[ct][jj][3])) & M23;
        *(uint2*)(Pw + (ct * 16 + col) * 68 + jj * 16 + quad * 4) = pk;
      }
    }

    // O^T += V^T P^T ; l += ones * P^T (denominator by MFMA)
    #pragma unroll
    for (int jp = 0; jp < 2; ++jp) {
      bf16x8 bP0 = ldfrag2(Pw + col * 68 + jp * 32 + quad * 8);
      bf16x8 bP1 = ldfrag2(Pw + (16 + col) * 68 + jp * 32 + quad * 8);
      lacc[0] = MFMA16x16x32(ones, bP0, lacc[0]);
      lacc[1] = MFMA16x16x32(ones, bP1, lacc[1]);
      #pragma unroll
      for (int dt = 0; dt < 4; ++dt) {
        bf16x8 av = ldfrag(Vs + (dt * 16 + col) * 128 + (((g * 8 + jp * 4 + quad) ^ col) * 8));
        o[0][dt] = MFMA16x16x32(av, bP0, o[0][dt]);
        o[1][dt] = MFMA16x16x32(av, bP1, o[1][dt]);
      }
    }
  }

  // combine wave-pair partials (additive: no online-max rescaling exists)
  __syncthreads();
  float* Rb = (float*)(&Ps[0][0]);
  float* Ro = Rb + u * 2048 + lane * 32;         // 32 f32/lane, 16B-aligned
  float* Rl = Rb + 8192 + u * 128 + lane * 2;
  if (g == 1) {
    #pragma unroll
    for (int ct = 0; ct < 2; ++ct)
      #pragma unroll
      for (int dt = 0; dt < 4; ++dt)
        *(f32x4*)(Ro + ((ct * 4 + dt) ^ (lane & 7)) * 4) = o[ct][dt];
    Rl[0] = lacc[0][0]; Rl[1] = lacc[1][0];
  }
  __syncthreads();
  if (g == 0) {
    float rl[2];
    #pragma unroll
    for (int ct = 0; ct < 2; ++ct) {
      #pragma unroll
      for (int dt = 0; dt < 4; ++dt)
        o[ct][dt] += *(const f32x4*)(Ro + ((ct * 4 + dt) ^ (lane & 7)) * 4);
      rl[ct] = 1.0f / (lacc[ct][0] + Rl[ct]);
    }
    #pragma unroll
    for (int ct = 0; ct < 2; ++ct) {
      const int q = qw + ct * 16 + col;
      #pragma unroll
      for (int dt = 0; dt < 4; ++dt) {
        u16x4 v;
        #pragma unroll
        for (int r = 0; r < 4; ++r) v[r] = f2bf(o[ct][dt][r] * rl[ct]);
        *(u16x4*)(AO + (size_t)(b * 2048 + q) * 1024 + h * 64 + dt * 16 + quad * 4) = v;
      }
    }
  }
}

// ---------------- output projection: out = AO * Wout^T + bout (fp32 out) ----------------
// Same BK=64 + swizzle + swapped-operand structure; f32x4 stores.
__global__ __launch_bounds__(256) void proj_gemm(
    const u16* __restrict__ A, const u16* __restrict__ Bw,
    const float* __restrict__ bias, float* __restrict__ out) {
  __shared__ __align__(16) u16 As[128 * 64];
  __shared__ __align__(16) u16 Bs[128 * 64];

  const int t = threadIdx.x;
  const int lane = t & 63, w = t >> 6;
  const int quad = lane >> 4, col = lane & 15;
  const int wm = w & 1, wn = w >> 1;
  const int m0 = blockIdx.y * 128, n0 = blockIdx.x * 128;

  f32x4 acc[4][4] = {};

  for (int kt = 0; kt < 16; ++kt) {
    const int ko = kt * 64;
    __syncthreads();
    #pragma unroll
    for (int p = 0; p < 4; ++p) {
      int c = t + 256 * p;
      int r = c >> 3, cc = c & 7;
      int so = ko + ((cc ^ (r & 7)) * 8);
      gl2lds16(A  + (size_t)(m0 + r) * 1024 + so, As + c * 8);
      gl2lds16(Bw + (size_t)(n0 + r) * 1024 + so, Bs + c * 8);
    }
    __syncthreads();

    #pragma unroll
    for (int kk = 0; kk < 2; ++kk) {
      const int e8 = ((kk * 4 + quad) ^ (col & 7)) * 8;
      bf16x8 bfr[4];
      #pragma unroll
      for (int j = 0; j < 4; ++j)
        bfr[j] = ldfrag(Bs + (wn * 64 + j * 16 + col) * 64 + e8);
      #pragma unroll
      for (int i = 0; i < 4; ++i) {
        bf16x8 afr = ldfrag(As + (wm * 64 + i * 16 + col) * 64 + e8);
        #pragma unroll
        for (int j = 0; j < 4; ++j)
          acc[i][j] = MFMA16x16x32(bfr[j], afr, acc[i][j]);  // C^T
      }
    }
  }

  const int nb = n0 + wn * 64;
  #pragma unroll
  for (int j = 0; j < 4; ++j) {
    const f32x4 b4 = *(const f32x4*)(bias + nb + j * 16 + quad * 4);
    #pragma unroll
    for (int i = 0; i < 4; ++i) {
      const int m = m0 + wm * 64 + i * 16 + col;
      f32x4 vv = acc[i][j] + b4;
      *(f32x4*)(out + (size_t)m * 1024 + nb + j * 16 + quad * 4) = vv;
    }
  }
}

extern "C" void kernel_launch(void* const* d_in, const int* in_sizes, int n_in,
                              void* d_out, int out_size, void* d_ws, size_t ws_size,
                              hipStream_t stream) {
  (void)in_sizes; (void)n_in; (void)out_size; (void)ws_size;
  const float* x    = (const float*)d_in[0];
  const int*   mask = (const int*)d_in[1];
  const float* Wqkv = (const float*)d_in[2];
  const float* bqkv = (const float*)d_in[3];
  const float* Wout = (const float*)d_in[4];
  const float* bout = (const float*)d_in[5];
  float* out = (float*)d_out;
  char* ws = (char*)d_ws;

  u16* Xb  = (u16*)(ws);                         // 8 MiB (reused as AO later)
  u16* Wqb = (u16*)(ws + ((size_t)8  << 20));    // 6 MiB
  u16* Wob = (u16*)(ws + ((size_t)14 << 20));    // 2 MiB
  u16* Qb  = (u16*)(ws + ((size_t)16 << 20));    // 8 MiB
  u16* Kb  = (u16*)(ws + ((size_t)24 << 20));    // 8 MiB
  u16* Vb  = (u16*)(ws + ((size_t)32 << 20));    // 8 MiB
  u16* Vtb = (u16*)(ws + ((size_t)40 << 20));    // 8 MiB  (total 48 MiB)
  u16* AO  = Xb;  // X is dead after qkv_gemm

  convert3<<<dim3(4096), dim3(256), 0, stream>>>(x, Wqkv, Wout, Xb, Wqb, Wob);
  qkv_gemm<<<dim3(24, 32), dim3(256), 0, stream>>>(Xb, Wqb, bqkv, Qb, Kb, Vb);
  transpose64<<<dim3(32, 32), dim3(256), 0, stream>>>(Vb, Vtb);
  attn<<<dim3(16, 32), dim3(512), 0, stream>>>(Qb, Kb, Vtb, mask, AO);
  proj_gemm<<<dim3(8, 32), dim3(256), 0, stream>>>(AO, Wob, bout, out);
}